// Round 2
// baseline (987.153 us; speedup 1.0000x reference)
//
#include <hip/hip_runtime.h>

typedef __attribute__((ext_vector_type(8))) short short8;
typedef __attribute__((ext_vector_type(4))) float f32x4;

#define MFMA16(a, b, c) __builtin_amdgcn_mfma_f32_16x16x32_bf16((a), (b), (c), 0, 0, 0)

static __device__ __forceinline__ unsigned short f2bf(float x) {
    unsigned int u = __builtin_bit_cast(unsigned int, x);
    unsigned int r = (u + 0x7FFFu + ((u >> 16) & 1u)) >> 16;
    return (unsigned short)r;
}
static __device__ __forceinline__ float bf2f(unsigned short h) {
    unsigned int u = ((unsigned int)h) << 16;
    return __builtin_bit_cast(float, u);
}

// ---------------- init: zero the stats accumulators ----------------
__global__ void k_init(float* stats) {
    if (threadIdx.x < 16) stats[threadIdx.x] = 0.0f;
}

// ---------------- gap: x [N,C,D,H,W] -> t0 [N,C,D] (mean over 256) ----------------
__global__ void k_gap(const float* __restrict__ x, float* __restrict__ t0) {
    int wv = threadIdx.x >> 6, l = threadIdx.x & 63;
    int row = blockIdx.x * 4 + wv;  // (n*2+c)*2048 + d
    float4 v = *(const float4*)(x + (size_t)row * 256 + l * 4);
    float s = v.x + v.y + v.z + v.w;
    #pragma unroll
    for (int m = 1; m < 64; m <<= 1) s += __shfl_xor(s, m, 64);
    if (l == 0) t0[row] = s * (1.0f / 256.0f);
}

// ------------- conv1 + BN + leaky + conv2 -> t2 [N,D,64]; accumulate LN stats -------------
__global__ void k_merge(const float* __restrict__ t0, const float* __restrict__ w1,
                        const float* __restrict__ gamma, const float* __restrict__ beta,
                        const float* __restrict__ mean, const float* __restrict__ var,
                        const float* __restrict__ w2, float* __restrict__ t2,
                        float* __restrict__ stats) {
    __shared__ float w2s[64][65];
    int tid = threadIdx.x, wv = tid >> 6, o = tid & 63;
    int n = blockIdx.y, d0 = blockIdx.x * 32;
    for (int i = tid; i < 4096; i += 256) w2s[i >> 6][i & 63] = w2[i];
    float w10 = w1[o * 2], w11 = w1[o * 2 + 1];
    float inv = gamma[o] * rsqrtf(var[o] + 1e-5f);
    float b2 = beta[o] - mean[o] * inv;
    __syncthreads();
    float ssum = 0.0f, ssq = 0.0f;
    for (int i = 0; i < 8; ++i) {
        int d = d0 + wv * 8 + i;
        float a = t0[(n * 2 + 0) * 2048 + d];
        float b = t0[(n * 2 + 1) * 2048 + d];
        float h = (w10 * a + w11 * b) * inv + b2;
        h = h > 0.0f ? h : 0.01f * h;
        float acc = 0.0f;
        for (int c = 0; c < 64; ++c) acc += w2s[o][c] * __shfl(h, c, 64);
        t2[((size_t)n * 2048 + d) * 64 + o] = acc;
        ssum += acc; ssq += acc * acc;
    }
    #pragma unroll
    for (int m = 1; m < 64; m <<= 1) {
        ssum += __shfl_xor(ssum, m, 64);
        ssq  += __shfl_xor(ssq, m, 64);
    }
    if (o == 0) { atomicAdd(&stats[n * 2], ssum); atomicAdd(&stats[n * 2 + 1], ssq); }
}

// ------------- LN (fused) + QKV projection; write bf16 hi/lo splits -------------
// Q,K: [hn=h*8+n][d][64] bf16 hi/lo.  V: transposed [hn][dd][d] bf16 hi/lo (via LDS).
__global__ __launch_bounds__(256) void k_qkv(
        const float* __restrict__ t2, const float* __restrict__ stats,
        const float* __restrict__ lnw, const float* __restrict__ lnb,
        const float* __restrict__ wq, const float* __restrict__ wk, const float* __restrict__ wvp,
        unsigned short* __restrict__ Qhi, unsigned short* __restrict__ Qlo,
        unsigned short* __restrict__ Khi, unsigned short* __restrict__ Klo,
        unsigned short* __restrict__ Vthi, unsigned short* __restrict__ Vtlo) {
    __shared__ float tl[16][64];
    __shared__ __align__(16) unsigned short vth[256][16];
    __shared__ __align__(16) unsigned short vtl[256][16];
    int tid = threadIdx.x;
    int n = blockIdx.y, d0 = blockIdx.x * 16;
    float mu = stats[n * 2] * (1.0f / 131072.0f);
    float ex2 = stats[n * 2 + 1] * (1.0f / 131072.0f);
    float rstd = rsqrtf(ex2 - mu * mu + 1e-6f);
    {
        int dd = tid >> 4, c0 = (tid & 15) * 4;
        float4 v = *(const float4*)(t2 + ((size_t)n * 2048 + d0 + dd) * 64 + c0);
        float vv[4] = {v.x, v.y, v.z, v.w};
        #pragma unroll
        for (int j = 0; j < 4; ++j) {
            int c = c0 + j;
            tl[dd][c] = (vv[j] - mu) * rstd * lnw[c * 2048 + d0 + dd] + lnb[c * 2048 + d0 + dd];
        }
    }
    __syncthreads();
    int o = tid;
    float aq[16], ak[16], av[16];
    #pragma unroll
    for (int d = 0; d < 16; ++d) { aq[d] = 0; ak[d] = 0; av[d] = 0; }
    for (int c = 0; c < 64; ++c) {
        float wqc = wq[o * 64 + c], wkc = wk[o * 64 + c], wvc = wvp[o * 64 + c];
        #pragma unroll
        for (int d = 0; d < 16; ++d) {
            float t = tl[d][c];
            aq[d] += wqc * t; ak[d] += wkc * t; av[d] += wvc * t;
        }
    }
    int h = o >> 6, dd2 = o & 63;
    size_t hn = (size_t)h * 8 + n;
    #pragma unroll
    for (int d = 0; d < 16; ++d) {
        size_t base = (hn * 2048 + d0 + d) * 64 + dd2;
        unsigned short qh = f2bf(aq[d]); Qhi[base] = qh; Qlo[base] = f2bf(aq[d] - bf2f(qh));
        unsigned short kh = f2bf(ak[d]); Khi[base] = kh; Klo[base] = f2bf(ak[d] - bf2f(kh));
        unsigned short vh = f2bf(av[d]); vth[o][d] = vh; vtl[o][d] = f2bf(av[d] - bf2f(vh));
    }
    __syncthreads();
    {
        size_t vrow = (hn * 64 + dd2) * 2048 + d0;
        uint4 a0 = *(uint4*)&vth[o][0];
        uint4 a1 = *(uint4*)&vth[o][8];
        *(uint4*)(Vthi + vrow) = a0;
        *(uint4*)(Vthi + vrow + 8) = a1;
        uint4 b0 = *(uint4*)&vtl[o][0];
        uint4 b1 = *(uint4*)&vtl[o][8];
        *(uint4*)(Vtlo + vrow) = b0;
        *(uint4*)(Vtlo + vrow + 8) = b1;
    }
}

// ------------- causal attention: att (normalized softmax, full matrix) + att_values -------------
// Block: (hn, qt'), 256 thr = 4 waves; wave owns 16 q rows. Two passes over k-tiles of 64.
// grid.x = hn so all 32 qt-blocks of one hn land on XCD hn%8 (32%8==0) -> K/V L2-resident.
// qt = 31 - blockIdx.y: heavy (high-qt) blocks dispatch first; light ones fill the tail.
// S = Q.K^T/64 via split-bf16 MFMA (3 products); PV via O^T = Vt . P^T (3 products).
__global__ __launch_bounds__(256) void k_attn(
        const unsigned short* __restrict__ Qhi, const unsigned short* __restrict__ Qlo,
        const unsigned short* __restrict__ Khi, const unsigned short* __restrict__ Klo,
        const unsigned short* __restrict__ Vthi, const unsigned short* __restrict__ Vtlo,
        float* __restrict__ att, float* __restrict__ attv) {
    __shared__ __align__(16) unsigned char smem[49152];
    // 0..8K: K hi | 8K..16K: K lo | 16K..24K: Vt hi | 24K..32K: Vt lo | 32K..48K: per-wave P hi/lo
    int tid = threadIdx.x;
    int wv = tid >> 6, l = tid & 63;
    int lo4 = l & 15, hi4 = l >> 4;
    int hn = blockIdx.x;
    int qt = 31 - blockIdx.y;
    int q0 = qt * 64, qw = q0 + wv * 16;
    size_t qkbase = (size_t)hn * 2048 * 64;

    // Q fragments (row-major, 8 contiguous bf16 along dh)
    short8 qfh[2], qfl[2];
    {
        int qrow = qw + lo4;
        #pragma unroll
        for (int ks = 0; ks < 2; ++ks) {
            size_t a = qkbase + (size_t)qrow * 64 + ks * 32 + hi4 * 8;
            qfh[ks] = *(const short8*)(Qhi + a);
            qfl[ks] = *(const short8*)(Qlo + a);
        }
    }

    float lsum[4] = {0, 0, 0, 0};
    // ---- pass 1: row sums of exp(s) (no max needed; |s| <~ 2.5) ----
    for (int kt = 0; kt <= qt; ++kt) {
        __syncthreads();
        #pragma unroll
        for (int rep = 0; rep < 2; ++rep) {
            int task = rep * 256 + tid;
            int kk = task >> 3, c = task & 7;
            int sw = kk * 128 + ((c * 16) ^ ((kk & 7) << 4));
            size_t g = qkbase + (size_t)(kt * 64 + kk) * 64 + c * 8;
            *(short8*)(smem + sw) = *(const short8*)(Khi + g);
            *(short8*)(smem + 8192 + sw) = *(const short8*)(Klo + g);
        }
        __syncthreads();
        #pragma unroll
        for (int n16 = 0; n16 < 4; ++n16) {
            f32x4 acc = {0.f, 0.f, 0.f, 0.f};
            int kk = n16 * 16 + lo4;
            #pragma unroll
            for (int ks = 0; ks < 2; ++ks) {
                int sw = kk * 128 + ((ks * 64 + hi4 * 16) ^ ((kk & 7) << 4));
                short8 kfh = *(const short8*)(smem + sw);
                short8 kfl = *(const short8*)(smem + 8192 + sw);
                acc = MFMA16(qfh[ks], kfh, acc);
                acc = MFMA16(qfh[ks], kfl, acc);
                acc = MFMA16(qfl[ks], kfh, acc);
            }
            int col = kt * 64 + n16 * 16 + lo4;
            #pragma unroll
            for (int r = 0; r < 4; ++r) {
                int row = qw + hi4 * 4 + r;
                if (col <= row) lsum[r] += __expf(acc[r] * 0.015625f);
            }
        }
    }
    float linv[4];
    #pragma unroll
    for (int r = 0; r < 4; ++r) {
        float s = lsum[r];
        s += __shfl_xor(s, 1, 64); s += __shfl_xor(s, 2, 64);
        s += __shfl_xor(s, 4, 64); s += __shfl_xor(s, 8, 64);
        linv[r] = 1.0f / s;
    }

    // ---- pass 2: recompute S, write normalized att, accumulate O = P.V ----
    f32x4 onn[4];
    #pragma unroll
    for (int i = 0; i < 4; ++i) onn[i] = (f32x4){0.f, 0.f, 0.f, 0.f};
    unsigned char* pbh = smem + 32768 + wv * 4096;
    unsigned char* pbl = pbh + 2048;

    for (int kt = 0; kt <= qt; ++kt) {
        __syncthreads();
        #pragma unroll
        for (int rep = 0; rep < 2; ++rep) {
            int task = rep * 256 + tid;
            int kk = task >> 3, c = task & 7;
            int sw = kk * 128 + ((c * 16) ^ ((kk & 7) << 4));
            size_t g = qkbase + (size_t)(kt * 64 + kk) * 64 + c * 8;
            *(short8*)(smem + sw) = *(const short8*)(Khi + g);
            *(short8*)(smem + 8192 + sw) = *(const short8*)(Klo + g);
            size_t gv = ((size_t)hn * 64 + kk) * 2048 + kt * 64 + c * 8;
            *(short8*)(smem + 16384 + sw) = *(const short8*)(Vthi + gv);
            *(short8*)(smem + 24576 + sw) = *(const short8*)(Vtlo + gv);
        }
        __syncthreads();
        #pragma unroll
        for (int n16 = 0; n16 < 4; ++n16) {
            f32x4 acc = {0.f, 0.f, 0.f, 0.f};
            int kk = n16 * 16 + lo4;
            #pragma unroll
            for (int ks = 0; ks < 2; ++ks) {
                int sw = kk * 128 + ((ks * 64 + hi4 * 16) ^ ((kk & 7) << 4));
                short8 kfh = *(const short8*)(smem + sw);
                short8 kfl = *(const short8*)(smem + 8192 + sw);
                acc = MFMA16(qfh[ks], kfh, acc);
                acc = MFMA16(qfh[ks], kfl, acc);
                acc = MFMA16(qfl[ks], kfh, acc);
            }
            #pragma unroll
            for (int r = 0; r < 4; ++r) {
                int row = qw + hi4 * 4 + r;
                int col = kt * 64 + n16 * 16 + lo4;
                float p = 0.0f;
                if (col <= row) p = __expf(acc[r] * 0.015625f) * linv[r];
                att[((size_t)(hn * 2048 + row)) * 2048 + col] = p;
                unsigned short ph = f2bf(p);
                unsigned short pl = f2bf(p - bf2f(ph));
                int prow = hi4 * 4 + r;
                int pby = prow * 128 + (((n16 * 16 + lo4) * 2) ^ ((prow & 7) << 4));
                *(unsigned short*)(pbh + pby) = ph;
                *(unsigned short*)(pbl + pby) = pl;
            }
        }
        // P fragments (B-operand: lane holds row q=lo4, 8 contiguous k)
        short8 pfh[2], pfl[2];
        #pragma unroll
        for (int ks = 0; ks < 2; ++ks) {
            int pby = lo4 * 128 + ((ks * 64 + hi4 * 16) ^ ((lo4 & 7) << 4));
            pfh[ks] = *(const short8*)(pbh + pby);
            pfl[ks] = *(const short8*)(pbl + pby);
        }
        #pragma unroll
        for (int dd16 = 0; dd16 < 4; ++dd16) {
            #pragma unroll
            for (int ks = 0; ks < 2; ++ks) {
                int vrow = dd16 * 16 + lo4;
                int vby = vrow * 128 + ((ks * 64 + hi4 * 16) ^ ((vrow & 7) << 4));
                short8 vfh = *(const short8*)(smem + 16384 + vby);
                short8 vfl = *(const short8*)(smem + 24576 + vby);
                onn[dd16] = MFMA16(vfh, pfh[ks], onn[dd16]);
                onn[dd16] = MFMA16(vfh, pfl[ks], onn[dd16]);
                onn[dd16] = MFMA16(vfl, pfh[ks], onn[dd16]);
            }
        }
    }

    // att_values: out[h,n,q,dd] -> attv[n, q, h*64+dd]
    {
        int n_ = hn & 7, h_ = hn >> 3;
        int q = qw + lo4;
        #pragma unroll
        for (int dd16 = 0; dd16 < 4; ++dd16) {
            size_t a = ((size_t)n_ * 2048 + q) * 256 + h_ * 64 + dd16 * 16 + hi4 * 4;
            *(f32x4*)(attv + a) = onn[dd16];
        }
    }

    // zero the strict upper region for this block's rows
    float4 z4 = make_float4(0.f, 0.f, 0.f, 0.f);
    for (int r = 0; r < 64; ++r) {
        size_t rowbase = ((size_t)(hn * 2048 + q0 + r)) * 2048;
        for (int c = q0 + 64 + tid * 4; c < 2048; c += 1024) {
            *(float4*)(att + rowbase + c) = z4;
        }
    }
}

// ------------- att_merge = att_values @ w_out.T -------------
__global__ void k_avmerge(const float* __restrict__ attv, const float* __restrict__ wout,
                          float* __restrict__ amerge) {
    int wv = threadIdx.x >> 6, l = threadIdx.x & 63;
    int row = blockIdx.x * 4 + wv;  // n*2048 + d
    float4 a = *(const float4*)(attv + (size_t)row * 256 + l * 4);
    float4 w = *(const float4*)(wout + l * 4);
    float s = a.x * w.x + a.y * w.y + a.z * w.z + a.w * w.w;
    #pragma unroll
    for (int m = 1; m < 64; m <<= 1) s += __shfl_xor(s, m, 64);
    if (l == 0) amerge[row] = s;
}

// ------------- y = x * att_merge (broadcast over c,h,w) -------------
__global__ void k_y(const float* __restrict__ x, const float* __restrict__ amerge,
                    float* __restrict__ y) {
    size_t i = (size_t)blockIdx.x * 256 + threadIdx.x;
    for (size_t idx = i; idx < 2097152; idx += 524288) {
        size_t row = idx >> 6;          // (n*2+c)*2048 + d
        int n = (int)(row >> 12);
        int d = (int)(row & 2047);
        float am = amerge[n * 2048 + d];
        float4 v = *(const float4*)(x + idx * 4);
        v.x *= am; v.y *= am; v.z *= am; v.w *= am;
        *(float4*)(y + idx * 4) = v;
    }
}

extern "C" void kernel_launch(void* const* d_in, const int* in_sizes, int n_in,
                              void* d_out, int out_size, void* d_ws, size_t ws_size,
                              hipStream_t stream) {
    const float* x        = (const float*)d_in[0];
    const float* conv1_w  = (const float*)d_in[1];
    const float* bn_gamma = (const float*)d_in[2];
    const float* bn_beta  = (const float*)d_in[3];
    const float* bn_mean  = (const float*)d_in[4];
    const float* bn_var   = (const float*)d_in[5];
    const float* conv2_w  = (const float*)d_in[6];
    const float* ln_w     = (const float*)d_in[7];
    const float* ln_b     = (const float*)d_in[8];
    const float* w_q      = (const float*)d_in[9];
    const float* w_k      = (const float*)d_in[10];
    const float* w_v      = (const float*)d_in[11];
    const float* w_out    = (const float*)d_in[12];

    float* ws = (float*)d_ws;
    float* stats = ws;                 // 16 floats
    float* t0 = ws + 16;               // 32768 floats
    float* t2 = ws + 16 + 32768;       // 1,048,576 floats
    unsigned short* ub = (unsigned short*)(ws + 1081360);
    const size_t B = 4194304;          // ushorts per buffer (8 MB)
    unsigned short* Qhi = ub;
    unsigned short* Qlo = ub + B;
    unsigned short* Khi = ub + 2 * B;
    unsigned short* Klo = ub + 3 * B;
    unsigned short* Vthi = ub + 4 * B;
    unsigned short* Vtlo = ub + 5 * B;

    float* out = (float*)d_out;
    float* y = out;                          // 8,388,608
    float* att = out + 8388608;              // 134,217,728
    float* attv = out + 142606336;           // 4,194,304
    float* amerge = out + 146800640;         // 16,384

    hipLaunchKernelGGL(k_init, dim3(1), dim3(64), 0, stream, stats);
    hipLaunchKernelGGL(k_gap, dim3(8192), dim3(256), 0, stream, x, t0);
    hipLaunchKernelGGL(k_merge, dim3(64, 8), dim3(256), 0, stream,
                       t0, conv1_w, bn_gamma, bn_beta, bn_mean, bn_var, conv2_w, t2, stats);
    hipLaunchKernelGGL(k_qkv, dim3(128, 8), dim3(256), 0, stream,
                       t2, stats, ln_w, ln_b, w_q, w_k, w_v,
                       Qhi, Qlo, Khi, Klo, Vthi, Vtlo);
    hipLaunchKernelGGL(k_attn, dim3(32, 32), dim3(256), 0, stream,
                       Qhi, Qlo, Khi, Klo, Vthi, Vtlo, att, attv);
    hipLaunchKernelGGL(k_avmerge, dim3(4096), dim3(256), 0, stream, attv, w_out, amerge);
    hipLaunchKernelGGL(k_y, dim3(2048), dim3(256), 0, stream, x, amerge, y);
}

// Round 11
// 848.001 us; speedup vs baseline: 1.1641x; 1.1641x over previous
//
#include <hip/hip_runtime.h>

typedef __attribute__((ext_vector_type(8))) short short8;
typedef __attribute__((ext_vector_type(4))) float f32x4;

#define MFMA16(a, b, c) __builtin_amdgcn_mfma_f32_16x16x32_bf16((a), (b), (c), 0, 0, 0)

static __device__ __forceinline__ unsigned short f2bf(float x) {
    unsigned int u = __builtin_bit_cast(unsigned int, x);
    unsigned int r = (u + 0x7FFFu + ((u >> 16) & 1u)) >> 16;
    return (unsigned short)r;
}
static __device__ __forceinline__ float bf2f(unsigned short h) {
    unsigned int u = ((unsigned int)h) << 16;
    return __builtin_bit_cast(float, u);
}

// ---------------- init: zero the stats accumulators ----------------
__global__ void k_init(float* stats) {
    if (threadIdx.x < 16) stats[threadIdx.x] = 0.0f;
}

// ---------------- gap: x [N,C,D,H,W] -> t0 [N,C,D] (mean over 256) ----------------
__global__ void k_gap(const float* __restrict__ x, float* __restrict__ t0) {
    int wv = threadIdx.x >> 6, l = threadIdx.x & 63;
    int row = blockIdx.x * 4 + wv;  // (n*2+c)*2048 + d
    float4 v = *(const float4*)(x + (size_t)row * 256 + l * 4);
    float s = v.x + v.y + v.z + v.w;
    #pragma unroll
    for (int m = 1; m < 64; m <<= 1) s += __shfl_xor(s, m, 64);
    if (l == 0) t0[row] = s * (1.0f / 256.0f);
}

// ---------------- transpose projection weights: w[256][64] -> wT[64][256] ----------------
__global__ void k_wt(const float* __restrict__ wq, const float* __restrict__ wk,
                     const float* __restrict__ wv, float* __restrict__ wqT,
                     float* __restrict__ wkT, float* __restrict__ wvT) {
    const float* s; float* d;
    if (blockIdx.x == 0)      { s = wq; d = wqT; }
    else if (blockIdx.x == 1) { s = wk; d = wkT; }
    else                      { s = wv; d = wvT; }
    for (int i = threadIdx.x; i < 2048; i += 256) {
        int idx = blockIdx.y * 2048 + i;
        int o = idx >> 6, c = idx & 63;
        d[c * 256 + o] = s[idx];
    }
}

// ------------- conv1 + BN + leaky + conv2 -> t2 [N,D,64]; accumulate LN stats -------------
__global__ void k_merge(const float* __restrict__ t0, const float* __restrict__ w1,
                        const float* __restrict__ gamma, const float* __restrict__ beta,
                        const float* __restrict__ mean, const float* __restrict__ var,
                        const float* __restrict__ w2, float* __restrict__ t2,
                        float* __restrict__ stats) {
    __shared__ float w2s[64][65];
    int tid = threadIdx.x, wv = tid >> 6, o = tid & 63;
    int n = blockIdx.y, d0 = blockIdx.x * 32;
    for (int i = tid; i < 4096; i += 256) w2s[i >> 6][i & 63] = w2[i];
    float w10 = w1[o * 2], w11 = w1[o * 2 + 1];
    float inv = gamma[o] * rsqrtf(var[o] + 1e-5f);
    float b2 = beta[o] - mean[o] * inv;
    __syncthreads();
    float ssum = 0.0f, ssq = 0.0f;
    for (int i = 0; i < 8; ++i) {
        int d = d0 + wv * 8 + i;
        float a = t0[(n * 2 + 0) * 2048 + d];
        float b = t0[(n * 2 + 1) * 2048 + d];
        float h = (w10 * a + w11 * b) * inv + b2;
        h = h > 0.0f ? h : 0.01f * h;
        float acc = 0.0f;
        for (int c = 0; c < 64; ++c) acc += w2s[o][c] * __shfl(h, c, 64);
        t2[((size_t)n * 2048 + d) * 64 + o] = acc;
        ssum += acc; ssq += acc * acc;
    }
    #pragma unroll
    for (int m = 1; m < 64; m <<= 1) {
        ssum += __shfl_xor(ssum, m, 64);
        ssq  += __shfl_xor(ssq, m, 64);
    }
    if (o == 0) { atomicAdd(&stats[n * 2], ssum); atomicAdd(&stats[n * 2 + 1], ssq); }
}

// ------------- LN (fused) + QKV projection; write bf16 hi/lo splits -------------
// Uses TRANSPOSED weights wT[64][256] so the per-c reads are coalesced across lanes.
__global__ __launch_bounds__(256) void k_qkv(
        const float* __restrict__ t2, const float* __restrict__ stats,
        const float* __restrict__ lnw, const float* __restrict__ lnb,
        const float* __restrict__ wqT, const float* __restrict__ wkT, const float* __restrict__ wvT,
        unsigned short* __restrict__ Qhi, unsigned short* __restrict__ Qlo,
        unsigned short* __restrict__ Khi, unsigned short* __restrict__ Klo,
        unsigned short* __restrict__ Vthi, unsigned short* __restrict__ Vtlo) {
    __shared__ float tl[16][64];
    __shared__ __align__(16) unsigned short vth[256][16];
    __shared__ __align__(16) unsigned short vtl[256][16];
    int tid = threadIdx.x;
    int n = blockIdx.y, d0 = blockIdx.x * 16;
    float mu = stats[n * 2] * (1.0f / 131072.0f);
    float ex2 = stats[n * 2 + 1] * (1.0f / 131072.0f);
    float rstd = rsqrtf(ex2 - mu * mu + 1e-6f);
    {
        int dd = tid >> 4, c0 = (tid & 15) * 4;
        float4 v = *(const float4*)(t2 + ((size_t)n * 2048 + d0 + dd) * 64 + c0);
        float vv[4] = {v.x, v.y, v.z, v.w};
        #pragma unroll
        for (int j = 0; j < 4; ++j) {
            int c = c0 + j;
            tl[dd][c] = (vv[j] - mu) * rstd * lnw[c * 2048 + d0 + dd] + lnb[c * 2048 + d0 + dd];
        }
    }
    __syncthreads();
    int o = tid;
    float aq[16], ak[16], av[16];
    #pragma unroll
    for (int d = 0; d < 16; ++d) { aq[d] = 0; ak[d] = 0; av[d] = 0; }
    for (int c = 0; c < 64; ++c) {
        float wqc = wqT[c * 256 + o], wkc = wkT[c * 256 + o], wvc = wvT[c * 256 + o];
        #pragma unroll
        for (int d = 0; d < 16; ++d) {
            float t = tl[d][c];
            aq[d] += wqc * t; ak[d] += wkc * t; av[d] += wvc * t;
        }
    }
    int h = o >> 6, dd2 = o & 63;
    size_t hn = (size_t)h * 8 + n;
    #pragma unroll
    for (int d = 0; d < 16; ++d) {
        size_t base = (hn * 2048 + d0 + d) * 64 + dd2;
        unsigned short qh = f2bf(aq[d]); Qhi[base] = qh; Qlo[base] = f2bf(aq[d] - bf2f(qh));
        unsigned short kh = f2bf(ak[d]); Khi[base] = kh; Klo[base] = f2bf(ak[d] - bf2f(kh));
        unsigned short vh = f2bf(av[d]); vth[o][d] = vh; vtl[o][d] = f2bf(av[d] - bf2f(vh));
    }
    __syncthreads();
    {
        size_t vrow = (hn * 64 + dd2) * 2048 + d0;
        uint4 a0 = *(uint4*)&vth[o][0];
        uint4 a1 = *(uint4*)&vth[o][8];
        *(uint4*)(Vthi + vrow) = a0;
        *(uint4*)(Vthi + vrow + 8) = a1;
        uint4 b0 = *(uint4*)&vtl[o][0];
        uint4 b1 = *(uint4*)&vtl[o][8];
        *(uint4*)(Vtlo + vrow) = b0;
        *(uint4*)(Vtlo + vrow + 8) = b1;
    }
}

// ------------- causal attention: att (normalized softmax, full matrix) + att_values -------------
// grid (hn=32, qt'=32): XCD = blockid%8 = hn%8 -> per-hn K/V stays in one XCD's L2.
// qt = 31 - blockIdx.y: heavy blocks dispatch first.
// T14 async-STAGE: issue next tile's global loads into regs right after writing the
// current tile's regs to LDS; HBM/L2 latency hides under MFMA+exp of current tile.
__global__ __launch_bounds__(256, 3) void k_attn(
        const unsigned short* __restrict__ Qhi, const unsigned short* __restrict__ Qlo,
        const unsigned short* __restrict__ Khi, const unsigned short* __restrict__ Klo,
        const unsigned short* __restrict__ Vthi, const unsigned short* __restrict__ Vtlo,
        float* __restrict__ att, float* __restrict__ attv) {
    __shared__ __align__(16) unsigned char smem[49152];
    // 0..8K: K hi | 8K..16K: K lo | 16K..24K: Vt hi | 24K..32K: Vt lo | 32K..48K: per-wave P hi/lo
    int tid = threadIdx.x;
    int wv = tid >> 6, l = tid & 63;
    int lo4 = l & 15, hi4 = l >> 4;
    int hn = blockIdx.x;
    int qt = 31 - blockIdx.y;
    int q0 = qt * 64, qw = q0 + wv * 16;
    size_t qkbase = (size_t)hn * 2048 * 64;

    // staging geometry (loop-invariant): rep0 covers kk 0..31, rep1 kk 32..63; same c both reps
    const int kk0 = tid >> 3, c0s = tid & 7;
    const int sw0 = kk0 * 128 + ((c0s * 16) ^ ((kk0 & 7) << 4));
    const int sw1 = sw0 + 4096;
    const size_t gK0 = qkbase + (size_t)kk0 * 64 + c0s * 8;         // + kt*4096
    const size_t gK1 = gK0 + 32 * 64;
    const size_t gV0 = (size_t)hn * 64 * 2048 + (size_t)kk0 * 2048 + c0s * 8;  // + kt*64
    const size_t gV1 = gV0 + 32 * 2048;

    // Q fragments (row-major, 8 contiguous bf16 along dh)
    short8 qfh[2], qfl[2];
    {
        int qrow = qw + lo4;
        #pragma unroll
        for (int ks = 0; ks < 2; ++ks) {
            size_t a = qkbase + (size_t)qrow * 64 + ks * 32 + hi4 * 8;
            qfh[ks] = *(const short8*)(Qhi + a);
            qfl[ks] = *(const short8*)(Qlo + a);
        }
    }

    short8 skh0, skh1, skl0, skl1;          // staged K regs (next tile)
    short8 svh0, svh1, svl0, svl1;          // staged V regs (next tile, pass 2)

    float lsum[4] = {0, 0, 0, 0};
    // ---- pass 1: row sums of exp(s) (no max needed; |s| <~ 2.5) ----
    {
        skh0 = *(const short8*)(Khi + gK0); skh1 = *(const short8*)(Khi + gK1);
        skl0 = *(const short8*)(Klo + gK0); skl1 = *(const short8*)(Klo + gK1);
    }
    for (int kt = 0; kt <= qt; ++kt) {
        __syncthreads();
        *(short8*)(smem + sw0) = skh0;        *(short8*)(smem + sw1) = skh1;
        *(short8*)(smem + 8192 + sw0) = skl0; *(short8*)(smem + 8192 + sw1) = skl1;
        if (kt < qt) {
            size_t o = (size_t)(kt + 1) * 4096;
            skh0 = *(const short8*)(Khi + gK0 + o); skh1 = *(const short8*)(Khi + gK1 + o);
            skl0 = *(const short8*)(Klo + gK0 + o); skl1 = *(const short8*)(Klo + gK1 + o);
        }
        __syncthreads();
        #pragma unroll
        for (int n16 = 0; n16 < 4; ++n16) {
            f32x4 acc = {0.f, 0.f, 0.f, 0.f};
            int kk = n16 * 16 + lo4;
            #pragma unroll
            for (int ks = 0; ks < 2; ++ks) {
                int sw = kk * 128 + ((ks * 64 + hi4 * 16) ^ ((kk & 7) << 4));
                short8 kfh = *(const short8*)(smem + sw);
                short8 kfl = *(const short8*)(smem + 8192 + sw);
                acc = MFMA16(qfh[ks], kfh, acc);
                acc = MFMA16(qfh[ks], kfl, acc);
                acc = MFMA16(qfl[ks], kfh, acc);
            }
            int col = kt * 64 + n16 * 16 + lo4;
            #pragma unroll
            for (int r = 0; r < 4; ++r) {
                int row = qw + hi4 * 4 + r;
                if (col <= row) lsum[r] += __expf(acc[r] * 0.015625f);
            }
        }
    }

    // issue pass-2 tile-0 loads before the linv reduction (latency hiding)
    {
        skh0 = *(const short8*)(Khi + gK0); skh1 = *(const short8*)(Khi + gK1);
        skl0 = *(const short8*)(Klo + gK0); skl1 = *(const short8*)(Klo + gK1);
        svh0 = *(const short8*)(Vthi + gV0); svh1 = *(const short8*)(Vthi + gV1);
        svl0 = *(const short8*)(Vtlo + gV0); svl1 = *(const short8*)(Vtlo + gV1);
    }
    float linv[4];
    #pragma unroll
    for (int r = 0; r < 4; ++r) {
        float s = lsum[r];
        s += __shfl_xor(s, 1, 64); s += __shfl_xor(s, 2, 64);
        s += __shfl_xor(s, 4, 64); s += __shfl_xor(s, 8, 64);
        linv[r] = 1.0f / s;
    }

    // ---- pass 2: recompute S, write normalized att, accumulate O = P.V ----
    f32x4 onn[4];
    #pragma unroll
    for (int i = 0; i < 4; ++i) onn[i] = (f32x4){0.f, 0.f, 0.f, 0.f};
    unsigned char* pbh = smem + 32768 + wv * 4096;
    unsigned char* pbl = pbh + 2048;

    for (int kt = 0; kt <= qt; ++kt) {
        __syncthreads();
        *(short8*)(smem + sw0) = skh0;         *(short8*)(smem + sw1) = skh1;
        *(short8*)(smem + 8192 + sw0) = skl0;  *(short8*)(smem + 8192 + sw1) = skl1;
        *(short8*)(smem + 16384 + sw0) = svh0; *(short8*)(smem + 16384 + sw1) = svh1;
        *(short8*)(smem + 24576 + sw0) = svl0; *(short8*)(smem + 24576 + sw1) = svl1;
        if (kt < qt) {
            size_t o = (size_t)(kt + 1) * 4096;
            size_t ov = (size_t)(kt + 1) * 64;
            skh0 = *(const short8*)(Khi + gK0 + o); skh1 = *(const short8*)(Khi + gK1 + o);
            skl0 = *(const short8*)(Klo + gK0 + o); skl1 = *(const short8*)(Klo + gK1 + o);
            svh0 = *(const short8*)(Vthi + gV0 + ov); svh1 = *(const short8*)(Vthi + gV1 + ov);
            svl0 = *(const short8*)(Vtlo + gV0 + ov); svl1 = *(const short8*)(Vtlo + gV1 + ov);
        }
        __syncthreads();
        #pragma unroll
        for (int n16 = 0; n16 < 4; ++n16) {
            f32x4 acc = {0.f, 0.f, 0.f, 0.f};
            int kk = n16 * 16 + lo4;
            #pragma unroll
            for (int ks = 0; ks < 2; ++ks) {
                int sw = kk * 128 + ((ks * 64 + hi4 * 16) ^ ((kk & 7) << 4));
                short8 kfh = *(const short8*)(smem + sw);
                short8 kfl = *(const short8*)(smem + 8192 + sw);
                acc = MFMA16(qfh[ks], kfh, acc);
                acc = MFMA16(qfh[ks], kfl, acc);
                acc = MFMA16(qfl[ks], kfh, acc);
            }
            #pragma unroll
            for (int r = 0; r < 4; ++r) {
                int row = qw + hi4 * 4 + r;
                int col = kt * 64 + n16 * 16 + lo4;
                float p = 0.0f;
                if (col <= row) p = __expf(acc[r] * 0.015625f) * linv[r];
                __builtin_nontemporal_store(p, att + ((size_t)(hn * 2048 + row)) * 2048 + col);
                unsigned short ph = f2bf(p);
                unsigned short pl = f2bf(p - bf2f(ph));
                int prow = hi4 * 4 + r;
                int pby = prow * 128 + (((n16 * 16 + lo4) * 2) ^ ((prow & 7) << 4));
                *(unsigned short*)(pbh + pby) = ph;
                *(unsigned short*)(pbl + pby) = pl;
            }
        }
        // P fragments (B-operand: lane holds row q=lo4, 8 contiguous k)
        short8 pfh[2], pfl[2];
        #pragma unroll
        for (int ks = 0; ks < 2; ++ks) {
            int pby = lo4 * 128 + ((ks * 64 + hi4 * 16) ^ ((lo4 & 7) << 4));
            pfh[ks] = *(const short8*)(pbh + pby);
            pfl[ks] = *(const short8*)(pbl + pby);
        }
        #pragma unroll
        for (int dd16 = 0; dd16 < 4; ++dd16) {
            #pragma unroll
            for (int ks = 0; ks < 2; ++ks) {
                int vrow = dd16 * 16 + lo4;
                int vby = vrow * 128 + ((ks * 64 + hi4 * 16) ^ ((vrow & 7) << 4));
                short8 vfh = *(const short8*)(smem + 16384 + vby);
                short8 vfl = *(const short8*)(smem + 24576 + vby);
                onn[dd16] = MFMA16(vfh, pfh[ks], onn[dd16]);
                onn[dd16] = MFMA16(vfh, pfl[ks], onn[dd16]);
                onn[dd16] = MFMA16(vfl, pfh[ks], onn[dd16]);
            }
        }
    }

    // att_values: out[h,n,q,dd] -> attv[n, q, h*64+dd]
    {
        int n_ = hn & 7, h_ = hn >> 3;
        int q = qw + lo4;
        #pragma unroll
        for (int dd16 = 0; dd16 < 4; ++dd16) {
            size_t a = ((size_t)n_ * 2048 + q) * 256 + h_ * 64 + dd16 * 16 + hi4 * 4;
            *(f32x4*)(attv + a) = onn[dd16];
        }
    }

    // zero the strict upper region for this block's rows (nontemporal vec4)
    f32x4 z4 = {0.f, 0.f, 0.f, 0.f};
    for (int r = 0; r < 64; ++r) {
        size_t rowbase = ((size_t)(hn * 2048 + q0 + r)) * 2048;
        for (int c = q0 + 64 + tid * 4; c < 2048; c += 1024) {
            __builtin_nontemporal_store(z4, (f32x4*)(att + rowbase + c));
        }
    }
}

// ------------- att_merge = att_values @ w_out.T -------------
__global__ void k_avmerge(const float* __restrict__ attv, const float* __restrict__ wout,
                          float* __restrict__ amerge) {
    int wv = threadIdx.x >> 6, l = threadIdx.x & 63;
    int row = blockIdx.x * 4 + wv;  // n*2048 + d
    float4 a = *(const float4*)(attv + (size_t)row * 256 + l * 4);
    float4 w = *(const float4*)(wout + l * 4);
    float s = a.x * w.x + a.y * w.y + a.z * w.z + a.w * w.w;
    #pragma unroll
    for (int m = 1; m < 64; m <<= 1) s += __shfl_xor(s, m, 64);
    if (l == 0) amerge[row] = s;
}

// ------------- y = x * att_merge (broadcast over c,h,w) -------------
__global__ void k_y(const float* __restrict__ x, const float* __restrict__ amerge,
                    float* __restrict__ y) {
    size_t i = (size_t)blockIdx.x * 256 + threadIdx.x;
    for (size_t idx = i; idx < 2097152; idx += 524288) {
        size_t row = idx >> 6;          // (n*2+c)*2048 + d
        int n = (int)(row >> 12);
        int d = (int)(row & 2047);
        float am = amerge[n * 2048 + d];
        f32x4 v = *(const f32x4*)(x + idx * 4);
        v *= am;
        __builtin_nontemporal_store(v, (f32x4*)(y + idx * 4));
    }
}

extern "C" void kernel_launch(void* const* d_in, const int* in_sizes, int n_in,
                              void* d_out, int out_size, void* d_ws, size_t ws_size,
                              hipStream_t stream) {
    const float* x        = (const float*)d_in[0];
    const float* conv1_w  = (const float*)d_in[1];
    const float* bn_gamma = (const float*)d_in[2];
    const float* bn_beta  = (const float*)d_in[3];
    const float* bn_mean  = (const float*)d_in[4];
    const float* bn_var   = (const float*)d_in[5];
    const float* conv2_w  = (const float*)d_in[6];
    const float* ln_w     = (const float*)d_in[7];
    const float* ln_b     = (const float*)d_in[8];
    const float* w_q      = (const float*)d_in[9];
    const float* w_k      = (const float*)d_in[10];
    const float* w_v      = (const float*)d_in[11];
    const float* w_out    = (const float*)d_in[12];

    float* ws = (float*)d_ws;
    float* stats = ws;                 // 16 floats
    float* t0 = ws + 16;               // 32768 floats
    float* t2 = ws + 16 + 32768;       // 1,048,576 floats
    float* wqT = ws + 1081360;         // 16384 floats
    float* wkT = wqT + 16384;
    float* wvT = wkT + 16384;
    unsigned short* ub = (unsigned short*)(wvT + 16384);
    const size_t B = 4194304;          // ushorts per buffer (8 MB)
    unsigned short* Qhi = ub;
    unsigned short* Qlo = ub + B;
    unsigned short* Khi = ub + 2 * B;
    unsigned short* Klo = ub + 3 * B;
    unsigned short* Vthi = ub + 4 * B;
    unsigned short* Vtlo = ub + 5 * B;

    float* out = (float*)d_out;
    float* y = out;                          // 8,388,608
    float* att = out + 8388608;              // 134,217,728
    float* attv = out + 142606336;           // 4,194,304
    float* amerge = out + 146800640;         // 16,384

    hipLaunchKernelGGL(k_init, dim3(1), dim3(64), 0, stream, stats);
    hipLaunchKernelGGL(k_wt, dim3(3, 8), dim3(256), 0, stream,
                       w_q, w_k, w_v, wqT, wkT, wvT);
    hipLaunchKernelGGL(k_gap, dim3(8192), dim3(256), 0, stream, x, t0);
    hipLaunchKernelGGL(k_merge, dim3(64, 8), dim3(256), 0, stream,
                       t0, conv1_w, bn_gamma, bn_beta, bn_mean, bn_var, conv2_w, t2, stats);
    hipLaunchKernelGGL(k_qkv, dim3(128, 8), dim3(256), 0, stream,
                       t2, stats, ln_w, ln_b, wqT, wkT, wvT,
                       Qhi, Qlo, Khi, Klo, Vthi, Vtlo);
    hipLaunchKernelGGL(k_attn, dim3(32, 32), dim3(256), 0, stream,
                       Qhi, Qlo, Khi, Klo, Vthi, Vtlo, att, attv);
    hipLaunchKernelGGL(k_avmerge, dim3(4096), dim3(256), 0, stream, attv, w_out, amerge);
    hipLaunchKernelGGL(k_y, dim3(2048), dim3(256), 0, stream, x, amerge, y);
}